// Round 5
// baseline (36.525 us; speedup 1.0000x reference)
//
#include <hip/hip_runtime.h>
#include <hip/hip_bf16.h>

#define N1    2001
#define EMB   64
#define NSHOW 5
#define MSONG 25
#define NPOS  (NSHOW * MSONG)   // 125
#define MAXU  128
#define NT    1024

__global__ __launch_bounds__(NT, 4)   // 4 waves/EU -> VGPR cap 128, no spill
void setsgnn_kernel(
    const int* __restrict__ song_ids,
    const int* __restrict__ prev_setlists,
    const int* __restrict__ venue_ids,
    const int* __restrict__ tour_ids,
    const int* __restrict__ country_ids,
    const int* __restrict__ is_festival,
    const int* __restrict__ is_marathon,
    const float* __restrict__ song_emb,
    const float* __restrict__ gcn_w1, const float* __restrict__ gcn_b1,
    const float* __restrict__ gcn_w2, const float* __restrict__ gcn_b2,
    const float* __restrict__ q_w,  const float* __restrict__ q_b,
    const float* __restrict__ k_w,  const float* __restrict__ k_b,
    const float* __restrict__ v_w,  const float* __restrict__ v_b,
    const float* __restrict__ venue_t, const float* __restrict__ tour_t,
    const float* __restrict__ country_t, const float* __restrict__ fest_t,
    const float* __restrict__ mara_t,
    const float* __restrict__ ctx_w, const float* __restrict__ ctx_b,
    const float* __restrict__ p1_w,  const float* __restrict__ p1_b,
    const float* __restrict__ p2_w,  const float* __restrict__ p2_b,
    const float* __restrict__ p3_w,  const float* __restrict__ p3_b,
    float* __restrict__ out)
{
    const int b    = blockIdx.x;
    const int tid  = threadIdx.x;
    const int wv   = tid >> 6;
    const int lane = tid & 63;

    __shared__ __align__(16) float xb0[MAXU][EMB];       // 32 KB
    __shared__ __align__(16) float xb1[MAXU][EMB];       // 32 KB
    __shared__ __align__(16) float wlds[2][EMB][EMB];    // 32 KB: gcn_w1/w2, later k_w/v_w
    __shared__ __align__(16) float blds[2][EMB];
    __shared__ __align__(16) float bias_ctx[EMB], bias_q[EMB], bias_k[EMB], bias_v[EMB];
    __shared__ __align__(16) float bias_p1[128], bias_p2[EMB], bias_p3w[EMB];
    __shared__ float bias_p3b;
    __shared__ unsigned short idmap[N1];
    __shared__ int   sl[NPOS];
    __shared__ int   pmap[NPOS];
    __shared__ int   list_ids[MAXU];
    __shared__ float c_us[MAXU][NSHOW];
    __shared__ float occv[MAXU];
    __shared__ float invv[MAXU];
    __shared__ float cntm1[NSHOW];
    __shared__ int   cnt_show[NSHOW];
    __shared__ int   U_cnt;
    __shared__ float Xsum[NSHOW][EMB];
    __shared__ float XW[NSHOW][EMB];
    __shared__ float show_e[NSHOW][EMB];
    __shared__ float ctxin[56];
    __shared__ float ctxv[EMB];
    __shared__ float qv[EMB];
    __shared__ float kvatt[NSHOW][EMB];
    __shared__ float vatt[NSHOW][EMB];
    __shared__ float attnw[NSHOW];
    __shared__ float hbuf[3 * EMB];
    __shared__ float h1b[128];
    __shared__ float h2b[EMB];
    __shared__ float partial[1024];

    // ---- issue long-latency loads FIRST (consumed much later -> hidden) ----
    const float4 g0 = ((const float4*)gcn_w1)[tid];   // 4096 floats = 1024 float4
    const float4 g1 = ((const float4*)gcn_w2)[tid];
    float4 bb;
    if (tid < 32) bb = (tid < 16) ? ((const float4*)gcn_b1)[tid]
                                  : ((const float4*)gcn_b2)[tid - 16];
    const int sid    = song_ids[b];
    const int vid    = venue_ids[b];
    const int tourid = tour_ids[b];
    const int cid    = country_ids[b];
    const int fid    = is_festival[b];
    const int mid    = is_marathon[b];

    // ---- Phase A: idmap init, setlist load, weights+biases to LDS ----
    for (int i = tid; i < N1; i += NT) idmap[i] = 0xFFFFu;
    if (tid < NPOS) sl[tid] = prev_setlists[b * NPOS + tid];
    if (tid == 0) U_cnt = 0;
    ((float4*)wlds)[tid]      = g0;     // wlds[0] = gcn_w1
    ((float4*)wlds)[NT + tid] = g1;     // wlds[1] = gcn_w2
    if (tid < 32) ((float4*)blds)[tid] = bb;
    // small biases -> LDS (all independent, issued in the same burst)
    {
        int r = tid - 256;
        if (r >= 0 && r < 16)        ((float4*)bias_ctx)[r]       = ((const float4*)ctx_b)[r];
        else if (r >= 16 && r < 32)  ((float4*)bias_q)[r - 16]    = ((const float4*)q_b)[r - 16];
        else if (r >= 32 && r < 48)  ((float4*)bias_k)[r - 32]    = ((const float4*)k_b)[r - 32];
        else if (r >= 48 && r < 64)  ((float4*)bias_v)[r - 48]    = ((const float4*)v_b)[r - 48];
        else if (r >= 64 && r < 96)  ((float4*)bias_p1)[r - 64]   = ((const float4*)p1_b)[r - 64];
        else if (r >= 96 && r < 112) ((float4*)bias_p2)[r - 96]   = ((const float4*)p2_b)[r - 96];
        else if (r >= 112 && r < 128)((float4*)bias_p3w)[r - 112] = ((const float4*)p3_w)[r - 112];
        else if (r == 128)           bias_p3b = p3_b[0];
    }
    __syncthreads();

    // ---- Phase B: mark active ids ----
    if (tid < NPOS) { int id = sl[tid]; if (id > 0) idmap[id] = 1u; }
    if (tid == 0) idmap[sid] = 1u;
    __syncthreads();

    // ---- Phase C: compact ----
    for (int i = tid; i < N1; i += NT) {
        if (idmap[i] == 1u) {
            int u = atomicAdd(&U_cnt, 1);
            idmap[i] = (unsigned short)u;
            list_ids[u] = i;
        }
    }
    __syncthreads();
    const int U = U_cnt;   // <= 126

    // ---- Phase D: pmap, zero c, cnt_show ----
    if (tid < NPOS) { int id = sl[tid]; pmap[tid] = (id > 0) ? (int)idmap[id] : -1; }
    for (int t = tid; t < MAXU * NSHOW; t += NT) ((float*)c_us)[t] = 0.f;
    if (tid < NSHOW) {
        int c = 0;
        for (int i = 0; i < MSONG; i++) c += (sl[tid * MSONG + i] > 0) ? 1 : 0;
        cnt_show[tid] = c; cntm1[tid] = (float)(c - 1);
    }
    __syncthreads();

    // ---- Phase D2: build c; gather x0 rows (zero-fill unused rows) ----
    if (tid < NPOS) { int pm = pmap[tid]; if (pm >= 0) atomicAdd(&c_us[pm][tid / MSONG], 1.f); }
    for (int t = tid; t < MAXU * (EMB / 4); t += NT) {
        int u = t >> 4, e4 = t & 15;
        float4 v = make_float4(0.f, 0.f, 0.f, 0.f);
        if (u < U) v = ((const float4*)(song_emb + list_ids[u] * EMB))[e4];
        *(float4*)&xb0[u][e4 * 4] = v;
    }
    __syncthreads();

    // ---- Phase D3: occ/inv per node; ctxin gather ----
    if (tid < MAXU) {
        float o = 0.f, r = 0.f;
        #pragma unroll
        for (int s = 0; s < NSHOW; s++) { float cc = c_us[tid][s]; o += cc; r += cc * cntm1[s]; }
        occv[tid] = o; invv[tid] = 1.f / (r + 1e-10f);
    }
    {
        int e = tid - MAXU;    // threads 128..183
        if (e >= 0 && e < 56) {
            float val;
            if (e < 16)      val = venue_t[vid * 16 + e];
            else if (e < 32) val = tour_t[tourid * 16 + (e - 16)];
            else if (e < 40) val = country_t[cid * 8 + (e - 32)];
            else if (e < 48) val = fest_t[fid * 8 + (e - 40)];
            else             val = mara_t[mid * 8 + (e - 48)];
            ctxin[e] = val;
        }
    }
    __syncthreads();

    // ---- CTX: ctx = ctxin @ ctx_w + ctx_b ----
    if (tid < EMB) {
        float acc = bias_ctx[tid];
        #pragma unroll
        for (int e = 0; e < 56; e++) acc += ctxin[e] * ctx_w[e * EMB + tid];
        ctxv[tid] = acc;
    }
    __syncthreads();

    // ---- Q (wave 0) + Xsum layer0 (waves 1..5) ----
    if (tid < EMB) {
        float acc = bias_q[tid];
        #pragma unroll
        for (int e = 0; e < EMB; e++) acc += ctxv[e] * q_w[e * EMB + tid];
        qv[tid] = acc;
    }
    if (tid >= EMB && tid < EMB + NSHOW * EMB) {
        int t = tid - EMB, s = t >> 6, e = t & 63;
        float acc = 0.f;
        #pragma unroll
        for (int i = 0; i < MSONG; i++) { int pm = pmap[s * MSONG + i]; if (pm >= 0) acc += xb0[pm][e]; }
        Xsum[s][e] = acc;
    }
    __syncthreads();

    // ---- GCN layers (no adjacency, no atomics): ----
    // out[u][col] = relu( (Sum_s c[u][s]*XW[s][col] - occ[u]*(x[u]@W)[col]) * inv[u] + b[col] )
    {
        float wcol[EMB];
        for (int l = 0; l < 2; ++l) {
            float (*xc)[EMB] = l ? xb1 : xb0;
            float (*xn)[EMB] = l ? xb0 : xb1;

            #pragma unroll
            for (int e = 0; e < EMB; e++) wcol[e] = wlds[l][e][lane];
            if (tid < NSHOW * EMB) {
                int s = tid >> 6, col = tid & 63;
                float acc = 0.f;
                #pragma unroll
                for (int e = 0; e < EMB; e++) acc += Xsum[s][e] * wlds[l][e][col];
                XW[s][col] = acc;
            }
            const float bias = blds[l][lane];
            __syncthreads();   // XW ready; wlds[l] fully consumed

            float4 kreg, vreg;
            if (l == 1) { kreg = ((const float4*)k_w)[tid]; vreg = ((const float4*)v_w)[tid]; }

            for (int u = wv; u < U; u += 16) {
                float a0 = 0.f, a1 = 0.f, a2 = 0.f, a3 = 0.f;
                #pragma unroll
                for (int e4 = 0; e4 < 16; e4++) {
                    const float4 a = *(const float4*)&xc[u][e4 * 4];
                    a0 += a.x * wcol[e4 * 4];
                    a1 += a.y * wcol[e4 * 4 + 1];
                    a2 += a.z * wcol[e4 * 4 + 2];
                    a3 += a.w * wcol[e4 * 4 + 3];
                }
                float y   = (a0 + a1) + (a2 + a3);
                float acc = c_us[u][0] * XW[0][lane] + c_us[u][1] * XW[1][lane]
                          + c_us[u][2] * XW[2][lane] + c_us[u][3] * XW[3][lane]
                          + c_us[u][4] * XW[4][lane];
                float val = (acc - occv[u] * y) * invv[u] + bias;
                xn[u][lane] = fmaxf(val, 0.f);
            }
            if (l == 1) { ((float4*)wlds)[tid] = kreg; ((float4*)wlds)[NT + tid] = vreg; }
            __syncthreads();

            if (l == 0) {
                if (tid < NSHOW * EMB) {
                    int s = tid >> 6, e = tid & 63;
                    float acc = 0.f;
                    #pragma unroll
                    for (int i = 0; i < MSONG; i++) { int pm = pmap[s * MSONG + i]; if (pm >= 0) acc += xb1[pm][e]; }
                    Xsum[s][e] = acc;
                }
                __syncthreads();
            }
        }
    }
    // final x2 in xb0; wlds[0]=k_w, wlds[1]=v_w

    // ---- T14 prefetch: issue p1/p2 weight loads now; consumed after attention ----
    const int kk1 = tid >> 7, o1 = tid & 127;   // p1 mapping
    const int kk2 = tid >> 6, o2 = lane;        // p2 mapping
    float p1wr[24], p2wr[8];
    #pragma unroll
    for (int j = 0; j < 24; j++) p1wr[j] = p1_w[(kk1 * 24 + j) * 128 + o1];
    #pragma unroll
    for (int j = 0; j < 8; j++)  p2wr[j] = p2_w[(kk2 * 8 + j) * 64 + o2];

    // ---- show embeddings ----
    if (tid < NSHOW * EMB) {
        int s = tid >> 6, e = tid & 63;
        float acc = 0.f;
        #pragma unroll
        for (int i = 0; i < MSONG; i++) { int pm = pmap[s * MSONG + i]; if (pm >= 0) acc += xb0[pm][e]; }
        int cs = cnt_show[s];
        show_e[s][e] = (cs > 0) ? acc / (float)cs : 0.f;
    }
    __syncthreads();

    // ---- K, V from LDS-staged weights ----
    if (tid < 2 * NSHOW * EMB) {
        int m = (tid >= NSHOW * EMB) ? 1 : 0;
        int t = m ? tid - NSHOW * EMB : tid;
        int s = t >> 6, col = t & 63;
        float acc = m ? bias_v[col] : bias_k[col];
        #pragma unroll
        for (int e = 0; e < EMB; e++) acc += show_e[s][e] * wlds[m][e][col];
        if (m) vatt[s][col] = acc; else kvatt[s][col] = acc;
    }
    __syncthreads();

    // ---- scores (waves 0..4, wave reduce) ----
    if (wv < NSHOW) {
        float p = qv[lane] * kvatt[wv][lane];
        #pragma unroll
        for (int o = 32; o > 0; o >>= 1) p += __shfl_xor(p, o, 64);
        if (lane == 0) attnw[wv] = p * 0.125f;
    }
    __syncthreads();
    if (tid == 0) {
        float mx = attnw[0];
        for (int s = 1; s < NSHOW; s++) mx = fmaxf(mx, attnw[s]);
        float sum = 0.f;
        for (int s = 0; s < NSHOW; s++) { float ev = expf(attnw[s] - mx); attnw[s] = ev; sum += ev; }
        float isum = 1.f / sum;
        for (int s = 0; s < NSHOW; s++) attnw[s] *= isum;
    }
    __syncthreads();

    // ---- attended + concat ----
    if (tid < EMB) {
        float acc = 0.f;
        #pragma unroll
        for (int s = 0; s < NSHOW; s++) acc += attnw[s] * vatt[s][tid];
        hbuf[2 * EMB + tid] = acc;
        hbuf[EMB + tid]     = ctxv[tid];
        hbuf[tid]           = xb0[(int)idmap[sid]][tid];
    }
    __syncthreads();

    // ---- p1 (192->128): split-k 8-way with prefetched weights ----
    {
        float acc = (kk1 == 0) ? bias_p1[o1] : 0.f;
        #pragma unroll
        for (int j = 0; j < 24; j++) acc += hbuf[kk1 * 24 + j] * p1wr[j];
        partial[kk1 * 128 + o1] = acc;
    }
    __syncthreads();
    if (tid < 128) {
        float acc = 0.f;
        #pragma unroll
        for (int kk = 0; kk < 8; kk++) acc += partial[kk * 128 + tid];
        h1b[tid] = fmaxf(acc, 0.f);
    }
    __syncthreads();

    // ---- p2 (128->64): split-k 16-way with prefetched weights ----
    {
        float acc = (kk2 == 0) ? bias_p2[o2] : 0.f;
        #pragma unroll
        for (int j = 0; j < 8; j++) acc += h1b[kk2 * 8 + j] * p2wr[j];
        partial[kk2 * 64 + o2] = acc;
    }
    __syncthreads();
    if (tid < 64) {
        float acc = 0.f;
        #pragma unroll
        for (int kk = 0; kk < 16; kk++) acc += partial[kk * 64 + tid];
        h2b[tid] = fmaxf(acc, 0.f);
    }
    __syncthreads();

    // ---- p3 (64->1) + sigmoid: wave 0 reduce ----
    if (wv == 0) {
        float p = h2b[lane] * bias_p3w[lane];
        #pragma unroll
        for (int o = 32; o > 0; o >>= 1) p += __shfl_xor(p, o, 64);
        if (lane == 0) out[b] = 1.f / (1.f + expf(-(p + bias_p3b)));
    }
}

extern "C" void kernel_launch(void* const* d_in, const int* in_sizes, int n_in,
                              void* d_out, int out_size, void* d_ws, size_t ws_size,
                              hipStream_t stream) {
    (void)n_in; (void)out_size; (void)d_ws; (void)ws_size;
    const int B = in_sizes[0];
    setsgnn_kernel<<<B, NT, 0, stream>>>(
        (const int*)d_in[0], (const int*)d_in[1], (const int*)d_in[2],
        (const int*)d_in[3], (const int*)d_in[4], (const int*)d_in[5],
        (const int*)d_in[6],
        (const float*)d_in[7],
        (const float*)d_in[8],  (const float*)d_in[9],
        (const float*)d_in[10], (const float*)d_in[11],
        (const float*)d_in[12], (const float*)d_in[13],
        (const float*)d_in[14], (const float*)d_in[15],
        (const float*)d_in[16], (const float*)d_in[17],
        (const float*)d_in[18], (const float*)d_in[19],
        (const float*)d_in[20], (const float*)d_in[21],
        (const float*)d_in[22],
        (const float*)d_in[23], (const float*)d_in[24],
        (const float*)d_in[25], (const float*)d_in[26],
        (const float*)d_in[27], (const float*)d_in[28],
        (const float*)d_in[29], (const float*)d_in[30],
        (float*)d_out);
}

// Round 6
// 32.896 us; speedup vs baseline: 1.1103x; 1.1103x over previous
//
#include <hip/hip_runtime.h>
#include <hip/hip_bf16.h>

#define N1    2001
#define EMB   64
#define NSHOW 5
#define MSONG 25
#define NPOS  (NSHOW * MSONG)   // 125
#define MAXU  128
#define NT    1024

__global__ __launch_bounds__(NT)
__attribute__((amdgpu_waves_per_eu(4, 4)))   // LDS forces 1 block/CU = 4 waves/EU; give allocator the 128-VGPR budget
void setsgnn_kernel(
    const int* __restrict__ song_ids,
    const int* __restrict__ prev_setlists,
    const int* __restrict__ venue_ids,
    const int* __restrict__ tour_ids,
    const int* __restrict__ country_ids,
    const int* __restrict__ is_festival,
    const int* __restrict__ is_marathon,
    const float* __restrict__ song_emb,
    const float* __restrict__ gcn_w1, const float* __restrict__ gcn_b1,
    const float* __restrict__ gcn_w2, const float* __restrict__ gcn_b2,
    const float* __restrict__ q_w,  const float* __restrict__ q_b,
    const float* __restrict__ k_w,  const float* __restrict__ k_b,
    const float* __restrict__ v_w,  const float* __restrict__ v_b,
    const float* __restrict__ venue_t, const float* __restrict__ tour_t,
    const float* __restrict__ country_t, const float* __restrict__ fest_t,
    const float* __restrict__ mara_t,
    const float* __restrict__ ctx_w, const float* __restrict__ ctx_b,
    const float* __restrict__ p1_w,  const float* __restrict__ p1_b,
    const float* __restrict__ p2_w,  const float* __restrict__ p2_b,
    const float* __restrict__ p3_w,  const float* __restrict__ p3_b,
    float* __restrict__ out)
{
    const int b    = blockIdx.x;
    const int tid  = threadIdx.x;
    const int wv   = tid >> 6;
    const int lane = tid & 63;

    __shared__ __align__(16) float xb0[MAXU][EMB];       // 32 KB
    __shared__ __align__(16) float xb1[MAXU][EMB];       // 32 KB
    __shared__ __align__(16) float wlds[2][EMB][EMB];    // 32 KB: gcn_w1/w2, later k_w/v_w
    __shared__ __align__(16) float blds[2][EMB];
    __shared__ __align__(16) float bias_ctx[EMB], bias_q[EMB], bias_k[EMB], bias_v[EMB];
    __shared__ __align__(16) float bias_p1[128], bias_p2[EMB], bias_p3w[EMB];
    __shared__ float bias_p3b;
    __shared__ unsigned short idmap[N1];
    __shared__ int   sl[NPOS];
    __shared__ int   pmap[NPOS];
    __shared__ int   list_ids[MAXU];
    __shared__ float c_us[MAXU][NSHOW];
    __shared__ float occv[MAXU];
    __shared__ float invv[MAXU];
    __shared__ float cntm1[NSHOW];
    __shared__ int   cnt_show[NSHOW];
    __shared__ int   U_cnt;
    __shared__ float Xsum[NSHOW][EMB];
    __shared__ float XW[NSHOW][EMB];
    __shared__ float show_e[NSHOW][EMB];
    __shared__ float ctxin[56];
    __shared__ float ctxv[EMB];
    __shared__ float qv[EMB];
    __shared__ float kvatt[NSHOW][EMB];
    __shared__ float vatt[NSHOW][EMB];
    __shared__ float attnw[NSHOW];
    __shared__ float hbuf[3 * EMB];
    __shared__ float h1b[128];
    __shared__ float h2b[EMB];
    __shared__ float partial[1024];

    // ---- issue long-latency loads FIRST (consumed much later -> hidden) ----
    const float4 g0 = ((const float4*)gcn_w1)[tid];   // 4096 floats = 1024 float4
    const float4 g1 = ((const float4*)gcn_w2)[tid];
    float4 bb;
    if (tid < 32) bb = (tid < 16) ? ((const float4*)gcn_b1)[tid]
                                  : ((const float4*)gcn_b2)[tid - 16];
    const int sid    = song_ids[b];
    const int vid    = venue_ids[b];
    const int tourid = tour_ids[b];
    const int cid    = country_ids[b];
    const int fid    = is_festival[b];
    const int mid    = is_marathon[b];

    // ---- Phase A: idmap init, setlist load, weights+biases to LDS ----
    for (int i = tid; i < N1; i += NT) idmap[i] = 0xFFFFu;
    if (tid < NPOS) sl[tid] = prev_setlists[b * NPOS + tid];
    if (tid == 0) U_cnt = 0;
    ((float4*)wlds)[tid]      = g0;     // wlds[0] = gcn_w1
    ((float4*)wlds)[NT + tid] = g1;     // wlds[1] = gcn_w2
    if (tid < 32) ((float4*)blds)[tid] = bb;
    {
        int r = tid - 256;
        if (r >= 0 && r < 16)        ((float4*)bias_ctx)[r]       = ((const float4*)ctx_b)[r];
        else if (r >= 16 && r < 32)  ((float4*)bias_q)[r - 16]    = ((const float4*)q_b)[r - 16];
        else if (r >= 32 && r < 48)  ((float4*)bias_k)[r - 32]    = ((const float4*)k_b)[r - 32];
        else if (r >= 48 && r < 64)  ((float4*)bias_v)[r - 48]    = ((const float4*)v_b)[r - 48];
        else if (r >= 64 && r < 96)  ((float4*)bias_p1)[r - 64]   = ((const float4*)p1_b)[r - 64];
        else if (r >= 96 && r < 112) ((float4*)bias_p2)[r - 96]   = ((const float4*)p2_b)[r - 96];
        else if (r >= 112 && r < 128)((float4*)bias_p3w)[r - 112] = ((const float4*)p3_w)[r - 112];
        else if (r == 128)           bias_p3b = p3_b[0];
    }
    __syncthreads();

    // ---- Phase B: mark active ids ----
    if (tid < NPOS) { int id = sl[tid]; if (id > 0) idmap[id] = 1u; }
    if (tid == 0) idmap[sid] = 1u;
    __syncthreads();

    // ---- Phase C: compact ----
    for (int i = tid; i < N1; i += NT) {
        if (idmap[i] == 1u) {
            int u = atomicAdd(&U_cnt, 1);
            idmap[i] = (unsigned short)u;
            list_ids[u] = i;
        }
    }
    __syncthreads();
    const int U = U_cnt;   // <= 126

    // ---- Phase D: pmap, zero c, cnt_show ----
    if (tid < NPOS) { int id = sl[tid]; pmap[tid] = (id > 0) ? (int)idmap[id] : -1; }
    for (int t = tid; t < MAXU * NSHOW; t += NT) ((float*)c_us)[t] = 0.f;
    if (tid < NSHOW) {
        int c = 0;
        for (int i = 0; i < MSONG; i++) c += (sl[tid * MSONG + i] > 0) ? 1 : 0;
        cnt_show[tid] = c; cntm1[tid] = (float)(c - 1);
    }
    __syncthreads();

    // ---- Phase D2: build c; gather x0 rows (zero-fill unused rows) ----
    if (tid < NPOS) { int pm = pmap[tid]; if (pm >= 0) atomicAdd(&c_us[pm][tid / MSONG], 1.f); }
    for (int t = tid; t < MAXU * (EMB / 4); t += NT) {
        int u = t >> 4, e4 = t & 15;
        float4 v = make_float4(0.f, 0.f, 0.f, 0.f);
        if (u < U) v = ((const float4*)(song_emb + list_ids[u] * EMB))[e4];
        *(float4*)&xb0[u][e4 * 4] = v;
    }
    __syncthreads();

    // ---- Phase D3: occ/inv per node; ctxin gather ----
    if (tid < MAXU) {
        float o = 0.f, r = 0.f;
        #pragma unroll
        for (int s = 0; s < NSHOW; s++) { float cc = c_us[tid][s]; o += cc; r += cc * cntm1[s]; }
        occv[tid] = o; invv[tid] = 1.f / (r + 1e-10f);
    }
    {
        int e = tid - MAXU;    // threads 128..183
        if (e >= 0 && e < 56) {
            float val;
            if (e < 16)      val = venue_t[vid * 16 + e];
            else if (e < 32) val = tour_t[tourid * 16 + (e - 16)];
            else if (e < 40) val = country_t[cid * 8 + (e - 32)];
            else if (e < 48) val = fest_t[fid * 8 + (e - 40)];
            else             val = mara_t[mid * 8 + (e - 48)];
            ctxin[e] = val;
        }
    }
    __syncthreads();

    // ---- CTX: ctx = ctxin @ ctx_w + ctx_b ----
    if (tid < EMB) {
        float acc = bias_ctx[tid];
        #pragma unroll
        for (int e = 0; e < 56; e++) acc += ctxin[e] * ctx_w[e * EMB + tid];
        ctxv[tid] = acc;
    }
    __syncthreads();

    // ---- Q (wave 0) + Xsum layer0 (waves 1..5) ----
    if (tid < EMB) {
        float acc = bias_q[tid];
        #pragma unroll
        for (int e = 0; e < EMB; e++) acc += ctxv[e] * q_w[e * EMB + tid];
        qv[tid] = acc;
    }
    if (tid >= EMB && tid < EMB + NSHOW * EMB) {
        int t = tid - EMB, s = t >> 6, e = t & 63;
        float acc = 0.f;
        #pragma unroll
        for (int i = 0; i < MSONG; i++) { int pm = pmap[s * MSONG + i]; if (pm >= 0) acc += xb0[pm][e]; }
        Xsum[s][e] = acc;
    }
    __syncthreads();

    // ---- GCN layers (no adjacency, no atomics): ----
    // out[u][col] = relu( (Sum_s c[u][s]*XW[s][col] - occ[u]*(x[u]@W)[col]) * inv[u] + b[col] )
    // Register pressure: weight column split into two 32-reg halves (K-split),
    // y[8] accumulators persistent; fully static indexing throughout.
    for (int l = 0; l < 2; ++l) {
        float (*xc)[EMB] = l ? xb1 : xb0;
        float (*xn)[EMB] = l ? xb0 : xb1;

        if (tid < NSHOW * EMB) {
            int s = tid >> 6, col = tid & 63;
            float acc = 0.f;
            #pragma unroll
            for (int e = 0; e < EMB; e++) acc += Xsum[s][e] * wlds[l][e][col];
            XW[s][col] = acc;
        }
        const float bias = blds[l][lane];
        __syncthreads();   // XW ready

        // layer 1: issue k_w/v_w restage loads now (written to LDS after compute)
        float4 kreg, vreg;
        if (l == 1) { kreg = ((const float4*)k_w)[tid]; vreg = ((const float4*)v_w)[tid]; }

        float y[8];
        #pragma unroll
        for (int h = 0; h < 2; ++h) {
            float wc[32];
            #pragma unroll
            for (int e = 0; e < 32; e++) wc[e] = wlds[l][h * 32 + e][lane];
            #pragma unroll
            for (int uu = 0; uu < 8; ++uu) {
                const int u = (uu << 4) | wv;     // covers 0..127
                float a0 = 0.f, a1 = 0.f, a2 = 0.f, a3 = 0.f;
                #pragma unroll
                for (int e4 = 0; e4 < 8; e4++) {
                    const float4 a = *(const float4*)&xc[u][h * 32 + e4 * 4];
                    a0 += a.x * wc[e4 * 4];
                    a1 += a.y * wc[e4 * 4 + 1];
                    a2 += a.z * wc[e4 * 4 + 2];
                    a3 += a.w * wc[e4 * 4 + 3];
                }
                float part = (a0 + a1) + (a2 + a3);
                y[uu] = h ? (y[uu] + part) : part;
            }
        }
        #pragma unroll
        for (int uu = 0; uu < 8; ++uu) {
            const int u = (uu << 4) | wv;
            float acc = c_us[u][0] * XW[0][lane] + c_us[u][1] * XW[1][lane]
                      + c_us[u][2] * XW[2][lane] + c_us[u][3] * XW[3][lane]
                      + c_us[u][4] * XW[4][lane];
            float val = (acc - occv[u] * y[uu]) * invv[u] + bias;
            xn[u][lane] = fmaxf(val, 0.f);
        }
        if (l == 1) { ((float4*)wlds)[tid] = kreg; ((float4*)wlds)[NT + tid] = vreg; }
        __syncthreads();

        if (l == 0) {
            if (tid < NSHOW * EMB) {
                int s = tid >> 6, e = tid & 63;
                float acc = 0.f;
                #pragma unroll
                for (int i = 0; i < MSONG; i++) { int pm = pmap[s * MSONG + i]; if (pm >= 0) acc += xb1[pm][e]; }
                Xsum[s][e] = acc;
            }
            __syncthreads();
        }
    }
    // final x2 in xb0; wlds[0]=k_w, wlds[1]=v_w

    // ---- T14 prefetch: issue p1/p2 weight loads now; consumed after attention ----
    const int kk1 = tid >> 7, o1 = tid & 127;   // p1 mapping
    const int kk2 = tid >> 6, o2 = lane;        // p2 mapping
    float p1wr[24], p2wr[8];
    #pragma unroll
    for (int j = 0; j < 24; j++) p1wr[j] = p1_w[(kk1 * 24 + j) * 128 + o1];
    #pragma unroll
    for (int j = 0; j < 8; j++)  p2wr[j] = p2_w[(kk2 * 8 + j) * 64 + o2];

    // ---- show embeddings ----
    if (tid < NSHOW * EMB) {
        int s = tid >> 6, e = tid & 63;
        float acc = 0.f;
        #pragma unroll
        for (int i = 0; i < MSONG; i++) { int pm = pmap[s * MSONG + i]; if (pm >= 0) acc += xb0[pm][e]; }
        int cs = cnt_show[s];
        show_e[s][e] = (cs > 0) ? acc / (float)cs : 0.f;
    }
    __syncthreads();

    // ---- K, V from LDS-staged weights ----
    if (tid < 2 * NSHOW * EMB) {
        int m = (tid >= NSHOW * EMB) ? 1 : 0;
        int t = m ? tid - NSHOW * EMB : tid;
        int s = t >> 6, col = t & 63;
        float acc = m ? bias_v[col] : bias_k[col];
        #pragma unroll
        for (int e = 0; e < EMB; e++) acc += show_e[s][e] * wlds[m][e][col];
        if (m) vatt[s][col] = acc; else kvatt[s][col] = acc;
    }
    __syncthreads();

    // ---- scores (waves 0..4, wave reduce) ----
    if (wv < NSHOW) {
        float p = qv[lane] * kvatt[wv][lane];
        #pragma unroll
        for (int o = 32; o > 0; o >>= 1) p += __shfl_xor(p, o, 64);
        if (lane == 0) attnw[wv] = p * 0.125f;
    }
    __syncthreads();
    if (tid == 0) {
        float mx = attnw[0];
        for (int s = 1; s < NSHOW; s++) mx = fmaxf(mx, attnw[s]);
        float sum = 0.f;
        for (int s = 0; s < NSHOW; s++) { float ev = expf(attnw[s] - mx); attnw[s] = ev; sum += ev; }
        float isum = 1.f / sum;
        for (int s = 0; s < NSHOW; s++) attnw[s] *= isum;
    }
    __syncthreads();

    // ---- attended + concat ----
    if (tid < EMB) {
        float acc = 0.f;
        #pragma unroll
        for (int s = 0; s < NSHOW; s++) acc += attnw[s] * vatt[s][tid];
        hbuf[2 * EMB + tid] = acc;
        hbuf[EMB + tid]     = ctxv[tid];
        hbuf[tid]           = xb0[(int)idmap[sid]][tid];
    }
    __syncthreads();

    // ---- p1 (192->128): split-k 8-way with prefetched weights ----
    {
        float acc = (kk1 == 0) ? bias_p1[o1] : 0.f;
        #pragma unroll
        for (int j = 0; j < 24; j++) acc += hbuf[kk1 * 24 + j] * p1wr[j];
        partial[kk1 * 128 + o1] = acc;
    }
    __syncthreads();
    if (tid < 128) {
        float acc = 0.f;
        #pragma unroll
        for (int kk = 0; kk < 8; kk++) acc += partial[kk * 128 + tid];
        h1b[tid] = fmaxf(acc, 0.f);
    }
    __syncthreads();

    // ---- p2 (128->64): split-k 16-way with prefetched weights ----
    {
        float acc = (kk2 == 0) ? bias_p2[o2] : 0.f;
        #pragma unroll
        for (int j = 0; j < 8; j++) acc += h1b[kk2 * 8 + j] * p2wr[j];
        partial[kk2 * 64 + o2] = acc;
    }
    __syncthreads();
    if (tid < 64) {
        float acc = 0.f;
        #pragma unroll
        for (int kk = 0; kk < 16; kk++) acc += partial[kk * 64 + tid];
        h2b[tid] = fmaxf(acc, 0.f);
    }
    __syncthreads();

    // ---- p3 (64->1) + sigmoid: wave 0 reduce ----
    if (wv == 0) {
        float p = h2b[lane] * bias_p3w[lane];
        #pragma unroll
        for (int o = 32; o > 0; o >>= 1) p += __shfl_xor(p, o, 64);
        if (lane == 0) out[b] = 1.f / (1.f + expf(-(p + bias_p3b)));
    }
}

extern "C" void kernel_launch(void* const* d_in, const int* in_sizes, int n_in,
                              void* d_out, int out_size, void* d_ws, size_t ws_size,
                              hipStream_t stream) {
    (void)n_in; (void)out_size; (void)d_ws; (void)ws_size;
    const int B = in_sizes[0];
    setsgnn_kernel<<<B, NT, 0, stream>>>(
        (const int*)d_in[0], (const int*)d_in[1], (const int*)d_in[2],
        (const int*)d_in[3], (const int*)d_in[4], (const int*)d_in[5],
        (const int*)d_in[6],
        (const float*)d_in[7],
        (const float*)d_in[8],  (const float*)d_in[9],
        (const float*)d_in[10], (const float*)d_in[11],
        (const float*)d_in[12], (const float*)d_in[13],
        (const float*)d_in[14], (const float*)d_in[15],
        (const float*)d_in[16], (const float*)d_in[17],
        (const float*)d_in[18], (const float*)d_in[19],
        (const float*)d_in[20], (const float*)d_in[21],
        (const float*)d_in[22],
        (const float*)d_in[23], (const float*)d_in[24],
        (const float*)d_in[25], (const float*)d_in[26],
        (const float*)d_in[27], (const float*)d_in[28],
        (const float*)d_in[29], (const float*)d_in[30],
        (float*)d_out);
}

// Round 7
// 30.929 us; speedup vs baseline: 1.1809x; 1.0636x over previous
//
#include <hip/hip_runtime.h>

#define N1    2001
#define EMB   64
#define NSHOW 5
#define MSONG 25
#define NPOS  (NSHOW * MSONG)   // 125
#define MAXU  128
#define NT    1024
#define WT    66                // transposed-weight row stride (bank-spread, 8B aligned)

__global__ __launch_bounds__(NT)
__attribute__((amdgpu_waves_per_eu(4, 4)))
void setsgnn_kernel(
    const int* __restrict__ song_ids,
    const int* __restrict__ prev_setlists,
    const int* __restrict__ venue_ids,
    const int* __restrict__ tour_ids,
    const int* __restrict__ country_ids,
    const int* __restrict__ is_festival,
    const int* __restrict__ is_marathon,
    const float* __restrict__ song_emb,
    const float* __restrict__ gcn_w1, const float* __restrict__ gcn_b1,
    const float* __restrict__ gcn_w2, const float* __restrict__ gcn_b2,
    const float* __restrict__ q_w,  const float* __restrict__ q_b,
    const float* __restrict__ k_w,  const float* __restrict__ k_b,
    const float* __restrict__ v_w,  const float* __restrict__ v_b,
    const float* __restrict__ venue_t, const float* __restrict__ tour_t,
    const float* __restrict__ country_t, const float* __restrict__ fest_t,
    const float* __restrict__ mara_t,
    const float* __restrict__ ctx_w, const float* __restrict__ ctx_b,
    const float* __restrict__ p1_w,  const float* __restrict__ p1_b,
    const float* __restrict__ p2_w,  const float* __restrict__ p2_b,
    const float* __restrict__ p3_w,  const float* __restrict__ p3_b,
    float* __restrict__ out)
{
    const int b    = blockIdx.x;
    const int tid  = threadIdx.x;
    const int wv   = tid >> 6;
    const int lane = tid & 63;

    __shared__ __align__(16) float xb0[MAXU][EMB];        // 32 KB (in-place GCN state)
    __shared__ __align__(16) float wldsT[2][EMB][WT];     // 33.8 KB transposed weights
    __shared__ __align__(16) float ctxw_l[56][EMB];       // 14 KB
    __shared__ __align__(16) float qw_l[EMB][EMB];        // 16 KB
    __shared__ __align__(16) float blds[2][EMB];
    __shared__ __align__(16) float bias_ctx[EMB], bias_q[EMB], bias_k[EMB], bias_v[EMB];
    __shared__ __align__(16) float bias_p1[128], bias_p2[EMB], bias_p3w[EMB];
    __shared__ float bias_p3b;
    __shared__ unsigned short idmap[N1];
    __shared__ int   sl[NPOS];
    __shared__ int   pmap[NPOS];
    __shared__ int   list_ids[MAXU];
    __shared__ float c_us[MAXU][NSHOW];
    __shared__ float occv[MAXU];
    __shared__ float invv[MAXU];
    __shared__ float cntm1[NSHOW];
    __shared__ int   cnt_show[NSHOW];
    __shared__ int   U_cnt;
    __shared__ float Xsum[NSHOW][EMB];
    __shared__ float XW[NSHOW][EMB];
    __shared__ float show_e[NSHOW][EMB];
    __shared__ float ctxin[56];
    __shared__ float ctxv[EMB];
    __shared__ float qv[EMB];
    __shared__ float kvatt[NSHOW][EMB];
    __shared__ float vatt[NSHOW][EMB];
    __shared__ float attnw[NSHOW];
    __shared__ float hbuf[3 * EMB];
    __shared__ float h1b[128];
    __shared__ float h2b[EMB];
    __shared__ float partial[1024];

    // ======== P0: issue all big global loads, stage to LDS ========
    const float4 g0  = ((const float4*)gcn_w1)[tid];
    const float4 g1  = ((const float4*)gcn_w2)[tid];
    const float4 qw4 = ((const float4*)q_w)[tid];
    float4 cw4 = make_float4(0.f, 0.f, 0.f, 0.f);
    if (tid < 896) cw4 = ((const float4*)ctx_w)[tid];
    float4 bb;
    if (tid < 32) bb = (tid < 16) ? ((const float4*)gcn_b1)[tid]
                                  : ((const float4*)gcn_b2)[tid - 16];
    const int slr = (tid < NPOS) ? prev_setlists[b * NPOS + tid] : 0;
    const int sid    = song_ids[b];
    const int vid    = venue_ids[b];
    const int tourid = tour_ids[b];
    const int cid    = country_ids[b];
    const int fid    = is_festival[b];
    const int mid    = is_marathon[b];

    for (int i = tid; i < N1; i += NT) idmap[i] = 0xFFFFu;
    for (int t = tid; t < MAXU * NSHOW; t += NT) ((float*)c_us)[t] = 0.f;
    if (tid < NPOS) sl[tid] = slr;
    if (tid == 0) U_cnt = 0;
    {   // transposed scatter of gcn weights: wldsT[l][out_col][in_e]
        const int e = tid >> 4, o0 = (tid * 4) & 63;
        wldsT[0][o0    ][e] = g0.x; wldsT[0][o0 + 1][e] = g0.y;
        wldsT[0][o0 + 2][e] = g0.z; wldsT[0][o0 + 3][e] = g0.w;
        wldsT[1][o0    ][e] = g1.x; wldsT[1][o0 + 1][e] = g1.y;
        wldsT[1][o0 + 2][e] = g1.z; wldsT[1][o0 + 3][e] = g1.w;
    }
    ((float4*)qw_l)[tid] = qw4;
    if (tid < 896) ((float4*)ctxw_l)[tid] = cw4;
    if (tid < 32) ((float4*)blds)[tid] = bb;
    {
        int r = tid - 256;
        if (r >= 0 && r < 16)        ((float4*)bias_ctx)[r]       = ((const float4*)ctx_b)[r];
        else if (r >= 16 && r < 32)  ((float4*)bias_q)[r - 16]    = ((const float4*)q_b)[r - 16];
        else if (r >= 32 && r < 48)  ((float4*)bias_k)[r - 32]    = ((const float4*)k_b)[r - 32];
        else if (r >= 48 && r < 64)  ((float4*)bias_v)[r - 48]    = ((const float4*)v_b)[r - 48];
        else if (r >= 64 && r < 96)  ((float4*)bias_p1)[r - 64]   = ((const float4*)p1_b)[r - 64];
        else if (r >= 96 && r < 112) ((float4*)bias_p2)[r - 96]   = ((const float4*)p2_b)[r - 96];
        else if (r >= 112 && r < 128)((float4*)bias_p3w)[r - 112] = ((const float4*)p3_w)[r - 112];
        else if (r == 128)           bias_p3b = p3_b[0];
    }
    __syncthreads();

    // ======== P1: mark active ids ========
    if (tid < NPOS) { int id = sl[tid]; if (id > 0) idmap[id] = 1u; }
    if (tid == 0) idmap[sid] = 1u;
    __syncthreads();

    // ======== P2: ballot compaction ========
    for (int i = tid; i < N1; i += NT) {
        const bool p = (idmap[i] == 1u);
        const unsigned long long m = __ballot(p);
        int base = 0;
        if (lane == 0) { int c = __popcll(m); if (c) base = atomicAdd(&U_cnt, c); }
        base = __shfl(base, 0, 64);
        if (p) {
            int r = __popcll(m & ((1ull << lane) - 1ull));
            int u = base + r;
            idmap[i] = (unsigned short)u;
            list_ids[u] = i;
        }
    }
    __syncthreads();
    const int U = U_cnt;   // <= 126

    // ======== P3: pmap + c build | cnt_show | ctxin | row gather ========
    if (tid < NPOS) {
        int id = sl[tid];
        int pm = (id > 0) ? (int)idmap[id] : -1;
        pmap[tid] = pm;
        if (pm >= 0) atomicAdd(&c_us[pm][tid / MSONG], 1.f);
    }
    if (tid >= 128 && tid < 128 + NSHOW) {
        int s = tid - 128, c = 0;
        for (int i = 0; i < MSONG; i++) c += (sl[s * MSONG + i] > 0) ? 1 : 0;
        cnt_show[s] = c; cntm1[s] = (float)(c - 1);
    }
    if (tid >= 144 && tid < 200) {
        int e = tid - 144; float val;
        if (e < 16)      val = venue_t[vid * 16 + e];
        else if (e < 32) val = tour_t[tourid * 16 + (e - 16)];
        else if (e < 40) val = country_t[cid * 8 + (e - 32)];
        else if (e < 48) val = fest_t[fid * 8 + (e - 40)];
        else             val = mara_t[mid * 8 + (e - 48)];
        ctxin[e] = val;
    }
    for (int t = tid; t < MAXU * (EMB / 4); t += NT) {
        int u = t >> 4, e4 = t & 15;
        float4 v = make_float4(0.f, 0.f, 0.f, 0.f);
        if (u < U) v = ((const float4*)(song_emb + list_ids[u] * EMB))[e4];
        *(float4*)&xb0[u][e4 * 4] = v;
    }
    __syncthreads();

    // ======== P4: occ/inv (tid<128) | ctx matmul (tid 128..191) | Xsum-L0 (waves 6..10) ========
    if (tid < MAXU) {
        float o = 0.f, r = 0.f;
        #pragma unroll
        for (int s = 0; s < NSHOW; s++) { float cc = c_us[tid][s]; o += cc; r += cc * cntm1[s]; }
        occv[tid] = o; invv[tid] = 1.f / (r + 1e-10f);
    }
    if (tid >= 128 && tid < 192) {
        int col = tid - 128;
        float acc = bias_ctx[col];
        #pragma unroll
        for (int e = 0; e < 56; e++) acc += ctxin[e] * ctxw_l[e][col];
        ctxv[col] = acc;
    }
    if (wv >= 6 && wv < 11) {
        int s = wv - 6;
        int pm[MSONG];
        #pragma unroll
        for (int i = 0; i < MSONG; i++) pm[i] = pmap[s * MSONG + i];
        float acc = 0.f;
        #pragma unroll
        for (int i = 0; i < MSONG; i++) if (pm[i] >= 0) acc += xb0[pm[i]][lane];
        Xsum[s][lane] = acc;
    }
    __syncthreads();

    // ======== P5: q (tid<64) | XW-L0 (tid 64..383) ========
    if (tid < EMB) {
        float acc = bias_q[tid];
        #pragma unroll
        for (int e = 0; e < EMB; e++) acc += ctxv[e] * qw_l[e][tid];
        qv[tid] = acc;
    }
    if (tid >= 64 && tid < 64 + NSHOW * EMB) {
        int t = tid - 64, s = t >> 6, col = t & 63;
        float acc = 0.f;
        #pragma unroll
        for (int e = 0; e < EMB; e += 2) {
            const float2 w2 = *(const float2*)&wldsT[0][col][e];
            acc += Xsum[s][e] * w2.x + Xsum[s][e + 1] * w2.y;
        }
        XW[s][col] = acc;
    }
    __syncthreads();

    // ======== P6: GCN layer 0 (in-place, 8-deep read batches) ========
    #define GCN_BODY(L)                                                          \
    {                                                                            \
        const float bias = blds[L][lane];                                        \
        float y[8] = {0.f,0.f,0.f,0.f,0.f,0.f,0.f,0.f};                          \
        _Pragma("unroll")                                                        \
        for (int e4 = 0; e4 < 16; ++e4) {                                        \
            float4 a[8];                                                         \
            _Pragma("unroll")                                                    \
            for (int uu = 0; uu < 8; ++uu)                                       \
                a[uu] = *(const float4*)&xb0[(uu << 4) | wv][e4 * 4];            \
            const float2 wa = *(const float2*)&wldsT[L][lane][e4 * 4];           \
            const float2 wb = *(const float2*)&wldsT[L][lane][e4 * 4 + 2];       \
            _Pragma("unroll")                                                    \
            for (int uu = 0; uu < 8; ++uu)                                       \
                y[uu] += a[uu].x * wa.x + a[uu].y * wa.y                         \
                       + a[uu].z * wb.x + a[uu].w * wb.y;                        \
        }                                                                        \
        _Pragma("unroll")                                                        \
        for (int uu = 0; uu < 8; ++uu) {                                         \
            const int u = (uu << 4) | wv;                                        \
            float acc = c_us[u][0] * XW[0][lane] + c_us[u][1] * XW[1][lane]      \
                      + c_us[u][2] * XW[2][lane] + c_us[u][3] * XW[3][lane]      \
                      + c_us[u][4] * XW[4][lane];                                \
            float val = (acc - occv[u] * y[uu]) * invv[u] + bias;                \
            xb0[u][lane] = fmaxf(val, 0.f);                                      \
        }                                                                        \
    }
    GCN_BODY(0)
    __syncthreads();

    // ======== P7: Xsum-L1 (waves 6..10) ========
    if (wv >= 6 && wv < 11) {
        int s = wv - 6;
        int pm[MSONG];
        #pragma unroll
        for (int i = 0; i < MSONG; i++) pm[i] = pmap[s * MSONG + i];
        float acc = 0.f;
        #pragma unroll
        for (int i = 0; i < MSONG; i++) if (pm[i] >= 0) acc += xb0[pm[i]][lane];
        Xsum[s][lane] = acc;
    }
    __syncthreads();

    // ======== P8: XW-L1 (tid 64..383) ========
    if (tid >= 64 && tid < 64 + NSHOW * EMB) {
        int t = tid - 64, s = t >> 6, col = t & 63;
        float acc = 0.f;
        #pragma unroll
        for (int e = 0; e < EMB; e += 2) {
            const float2 w2 = *(const float2*)&wldsT[1][col][e];
            acc += Xsum[s][e] * w2.x + Xsum[s][e + 1] * w2.y;
        }
        XW[s][col] = acc;
    }
    __syncthreads();

    // ======== P9: GCN layer 1 ========
    GCN_BODY(1)
    __syncthreads();

    // ======== P10: k/v restage + p1/p2 prefetch | show_e | hbuf cand+ctx ========
    const float4 kreg = ((const float4*)k_w)[tid];
    const float4 vreg = ((const float4*)v_w)[tid];
    const int kk1 = tid >> 7, o1 = tid & 127;
    const int kk2 = tid >> 6, o2 = lane;
    float p1wr[24], p2wr[8];
    #pragma unroll
    for (int j = 0; j < 24; j++) p1wr[j] = p1_w[(kk1 * 24 + j) * 128 + o1];
    #pragma unroll
    for (int j = 0; j < 8; j++)  p2wr[j] = p2_w[(kk2 * 8 + j) * 64 + o2];

    if (wv >= 6 && wv < 11) {
        int s = wv - 6;
        int pm[MSONG];
        #pragma unroll
        for (int i = 0; i < MSONG; i++) pm[i] = pmap[s * MSONG + i];
        float acc = 0.f;
        #pragma unroll
        for (int i = 0; i < MSONG; i++) if (pm[i] >= 0) acc += xb0[pm[i]][lane];
        int cs = cnt_show[s];
        show_e[s][lane] = (cs > 0) ? acc / (float)cs : 0.f;
    }
    if (tid < EMB)                      hbuf[tid] = xb0[(int)idmap[sid]][tid];
    else if (tid >= 64 && tid < 128)    hbuf[EMB + (tid - 64)] = ctxv[tid - 64];
    {   // write restaged k/v (transposed) — wldsT fully dead after P9
        const int e = tid >> 4, o0 = (tid * 4) & 63;
        wldsT[0][o0    ][e] = kreg.x; wldsT[0][o0 + 1][e] = kreg.y;
        wldsT[0][o0 + 2][e] = kreg.z; wldsT[0][o0 + 3][e] = kreg.w;
        wldsT[1][o0    ][e] = vreg.x; wldsT[1][o0 + 1][e] = vreg.y;
        wldsT[1][o0 + 2][e] = vreg.z; wldsT[1][o0 + 3][e] = vreg.w;
    }
    __syncthreads();

    // ======== P11: K,V (tid < 640) ========
    if (tid < 2 * NSHOW * EMB) {
        int m = (tid >= NSHOW * EMB) ? 1 : 0;
        int t = m ? tid - NSHOW * EMB : tid;
        int s = t >> 6, col = t & 63;
        float acc = m ? bias_v[col] : bias_k[col];
        #pragma unroll
        for (int e = 0; e < EMB; e += 2) {
            const float2 w2 = *(const float2*)&wldsT[m][col][e];
            acc += show_e[s][e] * w2.x + show_e[s][e + 1] * w2.y;
        }
        if (m) vatt[s][col] = acc; else kvatt[s][col] = acc;
    }
    __syncthreads();

    // ======== P12: scores ========
    if (wv < NSHOW) {
        float p = qv[lane] * kvatt[wv][lane];
        #pragma unroll
        for (int o = 32; o > 0; o >>= 1) p += __shfl_xor(p, o, 64);
        if (lane == 0) attnw[wv] = p * 0.125f;
    }
    __syncthreads();
    // ======== P13: softmax ========
    if (tid == 0) {
        float mx = attnw[0];
        for (int s = 1; s < NSHOW; s++) mx = fmaxf(mx, attnw[s]);
        float sum = 0.f;
        for (int s = 0; s < NSHOW; s++) { float ev = expf(attnw[s] - mx); attnw[s] = ev; sum += ev; }
        float isum = 1.f / sum;
        for (int s = 0; s < NSHOW; s++) attnw[s] *= isum;
    }
    __syncthreads();
    // ======== P14: attended ========
    if (tid < EMB) {
        float acc = 0.f;
        #pragma unroll
        for (int s = 0; s < NSHOW; s++) acc += attnw[s] * vatt[s][tid];
        hbuf[2 * EMB + tid] = acc;
    }
    __syncthreads();

    // ======== P15/16: p1 (192->128, split-k 8) ========
    {
        float acc = (kk1 == 0) ? bias_p1[o1] : 0.f;
        #pragma unroll
        for (int j = 0; j < 24; j++) acc += hbuf[kk1 * 24 + j] * p1wr[j];
        partial[kk1 * 128 + o1] = acc;
    }
    __syncthreads();
    if (tid < 128) {
        float acc = 0.f;
        #pragma unroll
        for (int kk = 0; kk < 8; kk++) acc += partial[kk * 128 + tid];
        h1b[tid] = fmaxf(acc, 0.f);
    }
    __syncthreads();

    // ======== P17/18: p2 (128->64, split-k 16) ========
    {
        float acc = (kk2 == 0) ? bias_p2[o2] : 0.f;
        #pragma unroll
        for (int j = 0; j < 8; j++) acc += h1b[kk2 * 8 + j] * p2wr[j];
        partial[kk2 * 64 + o2] = acc;
    }
    __syncthreads();
    if (tid < 64) {
        float acc = 0.f;
        #pragma unroll
        for (int kk = 0; kk < 16; kk++) acc += partial[kk * 64 + tid];
        h2b[tid] = fmaxf(acc, 0.f);
    }
    __syncthreads();

    // ======== P19: p3 + sigmoid ========
    if (wv == 0) {
        float p = h2b[lane] * bias_p3w[lane];
        #pragma unroll
        for (int o = 32; o > 0; o >>= 1) p += __shfl_xor(p, o, 64);
        if (lane == 0) out[b] = 1.f / (1.f + expf(-(p + bias_p3b)));
    }
}

extern "C" void kernel_launch(void* const* d_in, const int* in_sizes, int n_in,
                              void* d_out, int out_size, void* d_ws, size_t ws_size,
                              hipStream_t stream) {
    (void)n_in; (void)out_size; (void)d_ws; (void)ws_size;
    const int B = in_sizes[0];
    setsgnn_kernel<<<B, NT, 0, stream>>>(
        (const int*)d_in[0], (const int*)d_in[1], (const int*)d_in[2],
        (const int*)d_in[3], (const int*)d_in[4], (const int*)d_in[5],
        (const int*)d_in[6],
        (const float*)d_in[7],
        (const float*)d_in[8],  (const float*)d_in[9],
        (const float*)d_in[10], (const float*)d_in[11],
        (const float*)d_in[12], (const float*)d_in[13],
        (const float*)d_in[14], (const float*)d_in[15],
        (const float*)d_in[16], (const float*)d_in[17],
        (const float*)d_in[18], (const float*)d_in[19],
        (const float*)d_in[20], (const float*)d_in[21],
        (const float*)d_in[22],
        (const float*)d_in[23], (const float*)d_in[24],
        (const float*)d_in[25], (const float*)d_in[26],
        (const float*)d_in[27], (const float*)d_in[28],
        (const float*)d_in[29], (const float*)d_in[30],
        (float*)d_out);
}